// Round 6
// baseline (50.697 us; speedup 1.0000x reference)
//
#include <hip/hip_runtime.h>
#include <hip/hip_bf16.h>

// Problem constants (reference: B=64, Z=512, H=W=32 -> N=1024, Q=1)
#define B_ 64
#define Z_ 512
#define N_ 1024
#define LAM 1e-3f
#define SL 64       // column-slabs per sample (one block each)
#define NC 16       // pixel columns per block = N_/SL
#define TH 256      // threads per block (4 waves)
#define WS_XH (B_ * SL * Z_)   // floats: xh partials (8 MB)
#define WS_G  (B_ * SL)        // floats: g partials

// Block (b, sl): owns pixel columns [sl*16, sl*16+16) of sample b.
// Slab x[b, :, cols] (512 z x 16 cols = 32 KB) lives in REGISTERS:
//   thread t: jg = t&3 (4-col group), zr = t>>2 in [0,64); v[k] = float4 at
//   z = zr + 64k, k = 0..7. All 8 loads independent, issued upfront.
// Small blocks on purpose: 8 co-resident blocks/CU at independent phases so
// some block is always streaming loads while others compute (R3 had 4
// lockstep 512-thread blocks -> memory idle during barrier-synced tails).
// phase A: s[c] = sum_z W[z] x[z,c]; shfl_xor(4,8,16,32) wave-reduce,
//   4x16 LDS partials, 16-thread final -> h = sigmoid(s), g = sum h^2
// phase B: xh[z] = sum_c x[z,c] h[c]; register FMA, shfl_xor(1,2) over jg,
//   lane jg==0 stores the per-block partial. No atomics, no fences.
__global__ __launch_bounds__(TH, 8) void elm_k1(
    const float* __restrict__ x, const float* __restrict__ Wh,
    float* __restrict__ pxh, float* __restrict__ gws) {
  __shared__ float part[4][NC];   // per-wave phase-A partials (256 B)
  __shared__ float h_lds[NC];

  const int t   = threadIdx.x;
  const int blk = blockIdx.x;
  const int b   = blk >> 6;
  const int sl  = blk & 63;
  const int jg  = t & 3;          // column group (4 cols)
  const int zr  = t >> 2;         // z residue [0,64)
  const int wv  = t >> 6;         // wave id [0,4)
  const int ln  = t & 63;

  const float* xp = x + (size_t)b * (Z_ * N_) + (size_t)zr * N_ + (sl * NC + jg * 4);

  float4 v[8];
#pragma unroll
  for (int k = 0; k < 8; ++k)
    v[k] = *reinterpret_cast<const float4*>(xp + (size_t)(64 * k) * N_);

  float w[8];
#pragma unroll
  for (int k = 0; k < 8; ++k) w[k] = Wh[zr + 64 * k];

  // ---- phase A: per-thread partial s over this thread's 8 z's ----
  float sp[4];
#pragma unroll
  for (int i = 0; i < 4; ++i) {
    float s = 0.f;
#pragma unroll
    for (int k = 0; k < 8; ++k) s += w[k] * reinterpret_cast<const float*>(&v[k])[i];
    s += __shfl_xor(s, 4);       // reduce over lane bits 2..5 (zr within wave)
    s += __shfl_xor(s, 8);
    s += __shfl_xor(s, 16);
    s += __shfl_xor(s, 32);
    sp[i] = s;
  }
  if (ln < 4) {
#pragma unroll
    for (int i = 0; i < 4; ++i) part[wv][ln * 4 + i] = sp[i];
  }
  __syncthreads();

  if (t < NC) {
    float s = 0.f;
#pragma unroll
    for (int w4 = 0; w4 < 4; ++w4) s += part[w4][t];
    const float h = 1.f / (1.f + __expf(-s));
    h_lds[t] = h;
    float q = h * h;             // lanes 0..15 of wave 0
    q += __shfl_xor(q, 1);
    q += __shfl_xor(q, 2);
    q += __shfl_xor(q, 4);
    q += __shfl_xor(q, 8);
    if (t == 0) gws[blk] = q;
  }
  __syncthreads();

  // ---- phase B: xh[z] partials from registers ----
  float acc[8] = {0.f, 0.f, 0.f, 0.f, 0.f, 0.f, 0.f, 0.f};
#pragma unroll
  for (int i = 0; i < 4; ++i) {
    const float h = h_lds[jg * 4 + i];
#pragma unroll
    for (int k = 0; k < 8; ++k) acc[k] += h * reinterpret_cast<const float*>(&v[k])[i];
  }
#pragma unroll
  for (int k = 0; k < 8; ++k) {
    float a = acc[k];
    a += __shfl_xor(a, 1);
    a += __shfl_xor(a, 2);
    if (jg == 0) pxh[(size_t)blk * Z_ + zr + 64 * k] = a;
  }
}

// out[b, z] = (sum_sl pxh[b,sl,z]) / (sum_sl g[b,sl] + LAM)
__global__ __launch_bounds__(Z_) void elm_k2(
    const float* __restrict__ pxh, const float* __restrict__ gws,
    float* __restrict__ out) {
  const int b = blockIdx.x;
  const int t = threadIdx.x;
  __shared__ float ginv;
  if (t < 64) {
    float g = gws[b * SL + t];
    g += __shfl_xor(g, 1);
    g += __shfl_xor(g, 2);
    g += __shfl_xor(g, 4);
    g += __shfl_xor(g, 8);
    g += __shfl_xor(g, 16);
    g += __shfl_xor(g, 32);
    if (t == 0) ginv = 1.f / (g + LAM);
  }
  __syncthreads();
  float s = 0.f;
#pragma unroll
  for (int p = 0; p < SL; ++p) s += pxh[((size_t)b * SL + p) * Z_ + t];
  out[b * Z_ + t] = s * ginv;
}

extern "C" void kernel_launch(void* const* d_in, const int* in_sizes, int n_in,
                              void* d_out, int out_size, void* d_ws, size_t ws_size,
                              hipStream_t stream) {
  const float* x  = (const float*)d_in[0];
  const float* Wh = (const float*)d_in[1];
  float* out = (float*)d_out;
  float* pxh = (float*)d_ws;            // B_*SL*Z_ floats = 8 MB
  float* gws = (float*)d_ws + WS_XH;    // B_*SL floats

  elm_k1<<<dim3(B_ * SL), dim3(TH), 0, stream>>>(x, Wh, pxh, gws);
  elm_k2<<<dim3(B_), dim3(Z_), 0, stream>>>(pxh, gws, out);
}

// Round 7
// 29.126 us; speedup vs baseline: 1.7406x; 1.7406x over previous
//
#include <hip/hip_runtime.h>
#include <hip/hip_bf16.h>

// Problem constants (reference: B=64, Z=512, H=W=32 -> N=1024, Q=1)
#define B_ 64
#define Z_ 512
#define N_ 1024
#define LAM 1e-3f
#define PB 16       // column-slabs per sample (one block each)
#define NC 64       // pixel columns per block = N_/PB
#define TH 1024     // threads per block (16 waves)
#define WS_XH (B_ * PB * Z_)   // floats: xh partials (2 MB)
#define WS_G  (B_ * PB)        // floats: g partials

// Block (b, p): owns pixel columns [p*64, p*64+64) of sample b.
// Slab x[b, :, cols] (512 z x 64 cols = 128 KB) lives in REGISTERS:
//   thread t: jg = t&15 (4-col group -> 16 groups = 64 cols), zr = t>>4 in
//   [0,64); v[k] = float4 at z = zr + 64k, k = 0..7. All 8 loads independent.
// KEY vs R3: a wave's 64 lanes cover 4 z-rows x 16 groups -> 256 B contiguous
// per z-row (R3: 128 B, R6: 64 B -> 50.7 us). Fewer, longer DRAM bursts.
// phase A: s[c] = sum_z W[z] x[z,c]; shfl_xor(16,32) wave-reduce (zr bits),
//   16x64 LDS partials, 64-thread final -> h = sigmoid(s), g = sum h^2
// phase B: xh[z] = sum_c x[z,c] h[c]; register FMA, shfl_xor(1,2,4,8) over
//   jg bits, jg==0 lanes store per-block partials. No atomics, no fences.
__global__ __launch_bounds__(TH, 8) void elm_k1(
    const float* __restrict__ x, const float* __restrict__ Wh,
    float* __restrict__ pxh, float* __restrict__ gws) {
  __shared__ float part[16][NC];   // per-wave phase-A partials (4 KB)
  __shared__ float h_lds[NC];

  const int t   = threadIdx.x;
  const int blk = blockIdx.x;
  const int b   = blk >> 4;
  const int p   = blk & 15;
  const int jg  = t & 15;         // column group (4 cols)
  const int zr  = t >> 4;         // z residue [0,64)
  const int wv  = t >> 6;         // wave id [0,16)
  const int ln  = t & 63;         // lane: bits0..3 = jg, bits4..5 = zr&3

  const float* xp = x + (size_t)b * (Z_ * N_) + (size_t)zr * N_ + (p * NC + jg * 4);

  float4 v[8];
#pragma unroll
  for (int k = 0; k < 8; ++k)
    v[k] = *reinterpret_cast<const float4*>(xp + (size_t)(64 * k) * N_);

  float w[8];
#pragma unroll
  for (int k = 0; k < 8; ++k) w[k] = Wh[zr + 64 * k];

  // ---- phase A: per-thread partial s over this thread's 8 z's ----
  float sp[4];
#pragma unroll
  for (int i = 0; i < 4; ++i) {
    float s = 0.f;
#pragma unroll
    for (int k = 0; k < 8; ++k) s += w[k] * reinterpret_cast<const float*>(&v[k])[i];
    s += __shfl_xor(s, 16);      // reduce over zr&3 (lane bits 4..5)
    s += __shfl_xor(s, 32);
    sp[i] = s;
  }
  if (ln < 16) {                 // one lane per jg holds the wave's col sum
#pragma unroll
    for (int i = 0; i < 4; ++i) part[wv][ln * 4 + i] = sp[i];
  }
  __syncthreads();

  if (t < NC) {                  // 64 threads = all of wave 0
    float s = 0.f;
#pragma unroll
    for (int w16 = 0; w16 < 16; ++w16) s += part[w16][t];
    const float h = 1.f / (1.f + __expf(-s));
    h_lds[t] = h;
    float q = h * h;
    q += __shfl_xor(q, 1);
    q += __shfl_xor(q, 2);
    q += __shfl_xor(q, 4);
    q += __shfl_xor(q, 8);
    q += __shfl_xor(q, 16);
    q += __shfl_xor(q, 32);
    if (t == 0) gws[blk] = q;
  }
  __syncthreads();

  // ---- phase B: xh[z] partials from registers ----
  float acc[8] = {0.f, 0.f, 0.f, 0.f, 0.f, 0.f, 0.f, 0.f};
#pragma unroll
  for (int i = 0; i < 4; ++i) {
    const float h = h_lds[jg * 4 + i];
#pragma unroll
    for (int k = 0; k < 8; ++k) acc[k] += h * reinterpret_cast<const float*>(&v[k])[i];
  }
#pragma unroll
  for (int k = 0; k < 8; ++k) {
    float a = acc[k];
    a += __shfl_xor(a, 1);       // reduce across the 16 jg groups (bits 0..3)
    a += __shfl_xor(a, 2);
    a += __shfl_xor(a, 4);
    a += __shfl_xor(a, 8);
    if (jg == 0) pxh[(size_t)blk * Z_ + zr + 64 * k] = a;
  }
}

// out[b, z] = (sum_p pxh[b,p,z]) / (sum_p g[b,p] + LAM)
__global__ __launch_bounds__(Z_) void elm_k2(
    const float* __restrict__ pxh, const float* __restrict__ gws,
    float* __restrict__ out) {
  const int b = blockIdx.x;
  const int t = threadIdx.x;
  __shared__ float ginv;
  if (t < PB) {
    float g = gws[b * PB + t];
    g += __shfl_xor(g, 1);
    g += __shfl_xor(g, 2);
    g += __shfl_xor(g, 4);
    g += __shfl_xor(g, 8);
    if (t == 0) ginv = 1.f / (g + LAM);
  }
  __syncthreads();
  float s = 0.f;
#pragma unroll
  for (int p = 0; p < PB; ++p) s += pxh[((size_t)b * PB + p) * Z_ + t];
  out[b * Z_ + t] = s * ginv;
}

extern "C" void kernel_launch(void* const* d_in, const int* in_sizes, int n_in,
                              void* d_out, int out_size, void* d_ws, size_t ws_size,
                              hipStream_t stream) {
  const float* x  = (const float*)d_in[0];
  const float* Wh = (const float*)d_in[1];
  float* out = (float*)d_out;
  float* pxh = (float*)d_ws;            // B_*PB*Z_ floats = 2 MB
  float* gws = (float*)d_ws + WS_XH;    // B_*PB floats

  elm_k1<<<dim3(B_ * PB), dim3(TH), 0, stream>>>(x, Wh, pxh, gws);
  elm_k2<<<dim3(B_), dim3(Z_), 0, stream>>>(pxh, gws, out);
}